// Round 14
// baseline (2797.006 us; speedup 1.0000x reference)
//
#include <hip/hip_runtime.h>
#include <stdint.h>

#define Bn 128
#define Tn 256
#define En 300
#define Hn 1024
#define PADIDX 1
#define NBLK 256         // 2 groups x 128 col-blocks
#define NROT 16          // h buffer rotation depth (fresh address per step)
#define XSTRIDE 33       // xacc LDS row stride (pad: kills 4-way bank conflict)

typedef short s16x8 __attribute__((ext_vector_type(8)));
typedef float f32x4 __attribute__((ext_vector_type(4)));
typedef unsigned int u32;
typedef u32 u32x4 __attribute__((ext_vector_type(4)));

#define LDQ32(p) __hip_atomic_load((p), __ATOMIC_RELAXED, __HIP_MEMORY_SCOPE_SYSTEM)
#define ST32(p, v) __hip_atomic_store((p), (v), __ATOMIC_RELAXED, __HIP_MEMORY_SCOPE_SYSTEM)

__device__ __forceinline__ unsigned short f2bf(float f) {
  u32 u = __builtin_bit_cast(u32, f);
  u32 r = (u + 0x7fffu + ((u >> 16) & 1u)) >> 16;  // RNE
  return (unsigned short)r;
}
__device__ __forceinline__ float bf2f(unsigned short h) {
  u32 u = ((u32)h) << 16;
  return __builtin_bit_cast(float, u);
}
__device__ __forceinline__ float sigmoidf_(float x) { return 1.f / (1.f + __expf(-x)); }
__device__ __forceinline__ float tanhf_(float x) { return 1.f - 2.f / (__expf(2.f * x) + 1.f); }

// h load: sc0 only -> bypass L1, cache in XCD L2. NOT valid until manual s_waitcnt.
__device__ __forceinline__ u32x4 ldg_sc0_x4(const u32* p) {
  u32x4 r;
  asm volatile("global_load_dwordx4 %0, %1, off sc0" : "=v"(r) : "v"(p));
  return r;
}
#define WAITV24 do { asm volatile("s_waitcnt vmcnt(24)" ::: "memory"); \
                     __builtin_amdgcn_sched_barrier(0); } while (0)
#define WAITV16 do { asm volatile("s_waitcnt vmcnt(16)" ::: "memory"); \
                     __builtin_amdgcn_sched_barrier(0); } while (0)
#define WAITV8  do { asm volatile("s_waitcnt vmcnt(8)" ::: "memory");  \
                     __builtin_amdgcn_sched_barrier(0); } while (0)
#define WAITV0  do { asm volatile("s_waitcnt vmcnt(0)" ::: "memory");  \
                     __builtin_amdgcn_sched_barrier(0); } while (0)

// lane holds gate `gate` value v for its (b,unit); recover all 4 gates via shfl
__device__ __forceinline__ float gate_update(float pre, float& c, int gate) {
  float v = (gate == 2) ? tanhf_(pre) : sigmoidf_(pre);
  float vB = __shfl_xor(v, 4);
  float vC = __shfl_xor(v, 8);
  float vD = __shfl_xor(vB, 8);
  float i_ = (gate & 2) ? ((gate & 1) ? vD : vC) : ((gate & 1) ? vB : v);
  float f_ = (gate & 2) ? ((gate & 1) ? vC : vD) : ((gate & 1) ? v : vB);
  float g_ = (gate & 2) ? ((gate & 1) ? vB : v) : ((gate & 1) ? vD : vC);
  float o_ = (gate & 2) ? ((gate & 1) ? v : vB) : ((gate & 1) ? vC : vD);
  float cn = f_ * c + i_ * g_;
  c = cn;
  return o_ * tanhf_(cn);
}

// ---------------- K0: lengths -> tstar / padflag ----------------
__global__ void prep_kernel(const int* __restrict__ x, int* __restrict__ tstar,
                            int* __restrict__ padflag) {
  int b = threadIdx.x;
  if (b < Bn) {
    int len = 0;
    for (int t = 0; t < Tn; ++t) len += (x[b * Tn + t] != PADIDX) ? 1 : 0;
    int ts = (len > 0) ? (len - 1) : (Tn - 1);  // jax wraps index -1
    tstar[b] = ts;
    padflag[b] = (x[b * Tn + ts] == PADIDX) ? 1 : 0;
  }
}

// ---------------- K1: embedding gather, A-fragment-linear (R5/R10-verified) -----
// inp2[((t*8 + rg)*10 + ks)*64 + l][8] ; rg = group*4+q ; b = rg*16+(l&15) ;
// k = ks*32 + (l>>4)*8 + jj ; zero-padded past 300.
__global__ void gather2_kernel(const int* __restrict__ x, const float* __restrict__ embed,
                               unsigned short* __restrict__ inp2) {
  int idx = blockIdx.x * 256 + threadIdx.x;  // total 256*8*10*512 = 10,485,760
  int jj = idx & 7;
  int tmp = idx >> 3;
  int l = tmp & 63; tmp >>= 6;
  int ks = tmp % 10; tmp /= 10;
  int rg = tmp & 7;
  int t = tmp >> 3;
  int b = rg * 16 + (l & 15);
  int k = ks * 32 + (l >> 4) * 8 + jj;
  int tok = x[b * Tn + t];
  float v = (k < En) ? embed[(size_t)tok * En + k] : 0.f;
  inp2[idx] = f2bf(v);
}

// ---------------- K1b: W_ih -> bf16, B-fragment-linear keyed by (cb, ct, ks) ---
// wih3[((cb*2+ct)*10+ks)*512 + l*8 + jj]; row = ((l&15)>>2)*Hn + cb*8 + ((l&15)&3)
// + ct*4; k = ks*32 + (l>>4)*8 + jj ; zero-padded past 300.
__global__ void wih3_kernel(const float* __restrict__ Wih, unsigned short* __restrict__ wih3) {
  int idx = blockIdx.x * 256 + threadIdx.x;  // total 128*2*10*512 = 1,310,720
  int jj = idx & 7;
  int tmp = idx >> 3;
  int l = tmp & 63; tmp >>= 6;
  int ks = tmp % 10; tmp /= 10;     // tmp = cb*2 + ct
  int ct = tmp & 1, cb = tmp >> 1;
  int c16 = l & 15;
  int grow = (c16 >> 2) * Hn + cb * 8 + (c16 & 3) + ct * 4;
  int k = ks * 32 + (l >> 4) * 8 + jj;
  float v = (k < En) ? Wih[(size_t)grow * En + k] : 0.f;
  wih3[idx] = f2bf(v);
}

// ---------------- K2: persistent LSTM scan (producer-wave x-proj) ----------------
// 256 blocks x 320 thr (4 compute waves + 1 x-proj PRODUCER wave). group = bid>>7;
// 128 col-blocks/group, 8 units each. LDS: W_hh hi/lo (128 KB, 0-conflict
// fragment-linear) + xacc double buffer (2 x 8.25 KB f32). W_ih read by the
// producer from wih3 (global, L2-hot). h single bf16, block-major, rotation
// NROT=16, stores ST32 sc0sc1, loads sc0 — R13-proven. Sync = R10 barrier.
// Producer computes x_proj(t+1)+bias for all 64 batches x 32 cols into
// xacc[(t+1)&1] while consumers run recurrent(t); consumers init acc from
// xacc[t&1]. Barrier counts identical across all 5 waves.
__global__ __launch_bounds__(320, 1) void lstm_scan(
    const float* __restrict__ Whh, const unsigned short* __restrict__ wih3,
    const float* __restrict__ bih, const float* __restrict__ bhh,
    const unsigned short* __restrict__ inp2, const int* __restrict__ tstar,
    const int* __restrict__ padflag, unsigned short* __restrict__ h_pk,
    float* __restrict__ hsel, u32* __restrict__ flags) {
  // W elem index i = ks*1024 + ct*512 + lq*128 + lr*8 + j (contig per (ks,ct) read)
  __shared__ unsigned short lds_hi[32768];   // 64 KB  W_hh hi
  __shared__ unsigned short lds_lo[32768];   // 64 KB  W_hh lo
  __shared__ float xacc2[2][64 * XSTRIDE];   // 16.5 KB x-proj stage [b_loc][col32]

  const int bid = blockIdx.x;
  const int group = bid >> 7;              // 0: batches 0-63, 1: batches 64-127
  const int cb = bid & 127;                // col-block within group
  const int u0 = cb * 8;                   // 8 hidden units per block
  const int tid = threadIdx.x;

  // --- W_hh slice -> LDS hi/lo, fragment-linear (all 5 waves help) ---
  for (int i = tid; i < 32768; i += 320) {
    int j = i & 7, lr = (i >> 3) & 15, lq = (i >> 7) & 3, ct = (i >> 9) & 1, ks = i >> 10;
    int col = (lr >> 2) * Hn + u0 + (lr & 3) + ct * 4;
    int k = ks * 32 + lq * 8 + j;
    float w = Whh[(size_t)col * Hn + k];
    unsigned short hi = f2bf(w);
    lds_hi[i] = hi;
    lds_lo[i] = f2bf(w - bf2f(hi));
  }

  const int wv = tid >> 6, l = tid & 63;
  u32* const fg = flags + (group << 7);     // group's 128 per-block flags

  if (wv == 4) {
    // ================= PRODUCER WAVE =================
    const int c16 = l & 15;
    const int colg0 = (c16 >> 2) * Hn + u0 + (c16 & 3);    // ct=0 gate column
    const float biasx0 = bih[colg0] + bhh[colg0];
    const float biasx1 = bih[colg0 + 4] + bhh[colg0 + 4];
    const unsigned short* wB = wih3 + (size_t)cb * 10240 + l * 8;  // +ct*5120+ks*512
    const int rq = (l >> 4) * 4;   // C-row base within 16-batch quarter

#define XPROJ(TT, BUF)                                                           \
    {                                                                            \
      f32x4 xq[4][2];                                                            \
      _Pragma("unroll") for (int q = 0; q < 4; ++q) {                            \
        xq[q][0] = (f32x4){biasx0, biasx0, biasx0, biasx0};                      \
        xq[q][1] = (f32x4){biasx1, biasx1, biasx1, biasx1};                      \
      }                                                                          \
      _Pragma("unroll") for (int ks = 0; ks < 10; ++ks) {                        \
        s16x8 b0 = *(const s16x8*)(wB + ks * 512);                               \
        s16x8 b1 = *(const s16x8*)(wB + 5120 + ks * 512);                        \
        _Pragma("unroll") for (int q = 0; q < 4; ++q) {                          \
          const unsigned short* pa =                                             \
              inp2 + ((size_t)((TT) * 8 + group * 4 + q) * 10 + ks) * 512 + l * 8; \
          s16x8 a = *(const s16x8*)pa;                                           \
          xq[q][0] = __builtin_amdgcn_mfma_f32_16x16x32_bf16(a, b0, xq[q][0], 0, 0, 0); \
          xq[q][1] = __builtin_amdgcn_mfma_f32_16x16x32_bf16(a, b1, xq[q][1], 0, 0, 0); \
        }                                                                        \
      }                                                                          \
      _Pragma("unroll") for (int q = 0; q < 4; ++q)                              \
        _Pragma("unroll") for (int r = 0; r < 4; ++r) {                          \
          int brow = q * 16 + rq + r;                                            \
          xacc2[BUF][brow * XSTRIDE + c16] = xq[q][0][r];                        \
          xacc2[BUF][brow * XSTRIDE + 16 + c16] = xq[q][1][r];                   \
        }                                                                        \
    }

    XPROJ(0, 0)
    __syncthreads();                       // F: xacc[0] + W LDS ready
    for (int t = 0; t < Tn; ++t) {
      if (t) __syncthreads();              // B1 (release)
      if (t + 1 < Tn) { XPROJ(t + 1, (t + 1) & 1) }
      __syncthreads();                     // B2 (arrival)
    }
#undef XPROJ
    return;
  }

  // ================= CONSUMER WAVES (0-3) =================
  const int lr = l & 15;                    // A-row (batch) / D-col in tile
  const int lq = l >> 4;                    // quadrant
  const int usub = lr & 3, gate = lr >> 2;
  const int b0w = group * 64 + wv * 16;     // this wave's 16 batch rows
  const u32 lfrag = (u32)(lq * 256 + lr * 16);   // per-lane byte in 1 KB fragment
  const int st = cb & 7;                    // stagger: chunk start offset

  int tsr[4], pfr[4];
#pragma unroll
  for (int r = 0; r < 4; ++r) {
    int b = b0w + lq * 4 + r;
    tsr[r] = tstar[b];
    pfr[r] = padflag[b];
  }
  float creg0[4] = {0.f, 0.f, 0.f, 0.f};
  float creg1[4] = {0.f, 0.f, 0.f, 0.f};

  const char* base_hi = (const char*)lds_hi;
  const char* base_lo = (const char*)lds_lo;

  u32x4 qa[8][4];  // h prefetch: 8 chunk buffers x 4 ks x 16B (single bf16)

// block-major addressing (shorts): addr = (4*ks + lq)*1024 + b*8 + j
#define ISSUE_A(BUF, C)                                                          \
  _Pragma("unroll") for (int ii = 0; ii < 4; ++ii) {                             \
    qa[BUF][ii] = ldg_sc0_x4((const u32*)(hbase + ((C) * 4 + ii) * 4096));       \
  }
#define BODY_(BUF, C)                                                            \
  _Pragma("unroll") for (int ii = 0; ii < 4; ++ii) {                             \
    int ks = (C) * 4 + ii;                                                       \
    s16x8 ahi = __builtin_bit_cast(s16x8, qa[BUF][ii]);                          \
    u32 ob = (u32)ks * 2048 + lfrag;                                             \
    s16x8 bh0 = *(const s16x8*)(base_hi + ob);                                   \
    s16x8 bl0 = *(const s16x8*)(base_lo + ob);                                   \
    s16x8 bh1 = *(const s16x8*)(base_hi + ob + 1024);                            \
    s16x8 bl1 = *(const s16x8*)(base_lo + ob + 1024);                            \
    acc0 = __builtin_amdgcn_mfma_f32_16x16x32_bf16(ahi, bh0, acc0, 0, 0, 0);     \
    acc1 = __builtin_amdgcn_mfma_f32_16x16x32_bf16(ahi, bh1, acc1, 0, 0, 0);     \
    acc0 = __builtin_amdgcn_mfma_f32_16x16x32_bf16(ahi, bl0, acc0, 0, 0, 0);     \
    acc1 = __builtin_amdgcn_mfma_f32_16x16x32_bf16(ahi, bl1, acc1, 0, 0, 0);     \
  }

  __syncthreads();                         // F: xacc[0] + W LDS ready

  for (int t = 0; t < Tn; ++t) {
    // ---- acc init from producer's xacc (bias + x-proj already summed) ----
    const float* xs = &xacc2[t & 1][0];
    f32x4 acc0, acc1;
#pragma unroll
    for (int r = 0; r < 4; ++r) {
      int brow = wv * 16 + lq * 4 + r;
      acc0[r] = xs[brow * XSTRIDE + lr];
      acc1[r] = xs[brow * XSTRIDE + 16 + lr];
    }

    // ---- release: wave 0 polls the 128 flags; others sleep at the barrier ----
    if (t) {
      if (wv == 0) {
        u32 spins = 0;
        for (;;) {
          u32 f0 = LDQ32(fg + l);
          u32 f1 = LDQ32(fg + 64 + l);
          if (__ballot((f0 >= (u32)t) & (f1 >= (u32)t)) == ~0ull) break;
          __builtin_amdgcn_s_sleep(1);
          if (++spins > 400000u) break;  // watchdog: dead unless deadlock
        }
      }
      __syncthreads();                   // B1
    }
    WAITV0;  // clean vmcnt before counted prefetch chain

    // ---- recurrent K=1024: all 8 chunks issued upfront, staggered order ----
    const unsigned short* hbase = h_pk + (size_t)(t & (NROT - 1)) * (Bn * Hn) +
                                  (u32)(lq * 1024 + (b0w + lr) * 8);
    const int c0 = st, c1 = (st + 1) & 7, c2 = (st + 2) & 7, c3 = (st + 3) & 7;
    const int c4 = (st + 4) & 7, c5 = (st + 5) & 7, c6 = (st + 6) & 7, c7 = (st + 7) & 7;
    ISSUE_A(0, c0) ISSUE_A(1, c1) ISSUE_A(2, c2) ISSUE_A(3, c3)
    ISSUE_A(4, c4) ISSUE_A(5, c5) ISSUE_A(6, c6) ISSUE_A(7, c7)
    WAITV24; BODY_(0, c0) BODY_(1, c1)
    WAITV16; BODY_(2, c2) BODY_(3, c3)
    WAITV8;  BODY_(4, c4) BODY_(5, c5)
    WAITV0;  BODY_(6, c6) BODY_(7, c7)

    // ---- gates + state update; bf16 h, pair-packed ST32 (even usub lanes) ----
    unsigned short* const hout =
        h_pk + (size_t)((t + 1) & (NROT - 1)) * (Bn * Hn);
#pragma unroll
    for (int r = 0; r < 4; ++r) {
      float h0 = gate_update(acc0[r], creg0[r], gate);
      float h1 = gate_update(acc1[r], creg1[r], gate);
      u32 h0h = (u32)f2bf(h0);
      u32 h1h = (u32)f2bf(h1);
      u32 n0 = (u32)__shfl_xor((int)h0h, 1);   // neighbor usub^1 (convergent)
      u32 n1 = (u32)__shfl_xor((int)h1h, 1);
      if (gate == 0) {
        int b = b0w + lq * 4 + r;
        if ((usub & 1) == 0) {
          unsigned short* slice = hout + (u32)(cb * 1024 + b * 8);
          ST32((u32*)(slice + usub), h0h | (n0 << 16));
          ST32((u32*)(slice + usub + 4), h1h | (n1 << 16));
        }
        if (t == tsr[r]) {
          hsel[(size_t)b * Hn + u0 + usub] = pfr[r] ? 0.f : h0;
          hsel[(size_t)b * Hn + u0 + usub + 4] = pfr[r] ? 0.f : h1;
        }
      }
    }

    // ---- arrival: barrier (drains each wave's vmcnt), publish flag ----
    __syncthreads();                     // B2
    if (tid == 0) ST32(fg + cb, (u32)(t + 1));
    // every 8 steps: invalidate local L2/L1 h copies; guarantees no stale h line
    // survives to the address's reuse at t+16
    if ((t & 7) == 7) __builtin_amdgcn_fence(__ATOMIC_ACQUIRE, "agent");
  }
#undef ISSUE_A
#undef BODY_
}

// ---------------- K3: out[b][o] = hsel[b]·W_out[o] + b_out[o] ----------------
__global__ void head_kernel(const float* __restrict__ hsel, const float* __restrict__ Wout,
                            const float* __restrict__ bout, float* __restrict__ out) {
  int b = blockIdx.x;
  int l = threadIdx.x;  // 64 threads
  float s0 = 0.f, s1 = 0.f, s2 = 0.f;
  for (int j = l; j < Hn; j += 64) {
    float h = hsel[(size_t)b * Hn + j];
    s0 += h * Wout[j];
    s1 += h * Wout[Hn + j];
    s2 += h * Wout[2 * Hn + j];
  }
#pragma unroll
  for (int m = 32; m; m >>= 1) {
    s0 += __shfl_xor(s0, m);
    s1 += __shfl_xor(s1, m);
    s2 += __shfl_xor(s2, m);
  }
  if (l == 0) {
    out[b * 3 + 0] = s0 + bout[0];
    out[b * 3 + 1] = s1 + bout[1];
    out[b * 3 + 2] = s2 + bout[2];
  }
}

extern "C" void kernel_launch(void* const* d_in, const int* in_sizes, int n_in,
                              void* d_out, int out_size, void* d_ws, size_t ws_size,
                              hipStream_t stream) {
  const int* x = (const int*)d_in[0];
  const float* embed = (const float*)d_in[1];
  const float* Wih = (const float*)d_in[2];
  const float* Whh = (const float*)d_in[3];
  const float* bih = (const float*)d_in[4];
  const float* bhh = (const float*)d_in[5];
  const float* Wout = (const float*)d_in[6];
  const float* bout = (const float*)d_in[7];
  float* out = (float*)d_out;

  // ws layout
  const size_t INP2_BYTES = (size_t)Tn * 8 * 10 * 512 * 2;   // 20,971,520
  const size_t WIH3_BYTES = (size_t)128 * 2 * 10 * 512 * 2;  //  2,621,440
  const size_t HPK_BYTES = (size_t)NROT * Bn * Hn * 2;       //  4,194,304
  const size_t HSEL_BYTES = (size_t)Bn * Hn * 4;             //    524,288
  char* p = (char*)d_ws;
  unsigned short* inp2 = (unsigned short*)p;            p += INP2_BYTES;
  unsigned short* wih3 = (unsigned short*)p;            p += WIH3_BYTES;
  unsigned short* h_pk = (unsigned short*)p;            p += HPK_BYTES;
  float* hsel = (float*)p;                              p += HSEL_BYTES;
  int* tstar = (int*)p;                                 p += 512;
  int* padflag = (int*)p;                               p += 512;
  u32* flags = (u32*)p;                                 p += 1024;

  // per-launch init: h(0) = 0 (rotation slot 0), flags = 0 (self-contained replay)
  hipMemsetAsync(h_pk, 0, (size_t)Bn * Hn * 2, stream);
  hipMemsetAsync(flags, 0, 1024, stream);

  prep_kernel<<<1, 128, 0, stream>>>(x, tstar, padflag);
  gather2_kernel<<<40960, 256, 0, stream>>>(x, embed, inp2);
  wih3_kernel<<<5120, 256, 0, stream>>>(Wih, wih3);
  lstm_scan<<<NBLK, 320, 0, stream>>>(Whh, wih3, bih, bhh, inp2, tstar, padflag,
                                      h_pk, hsel, flags);
  head_kernel<<<Bn, 64, 0, stream>>>(hsel, Wout, bout, out);
}

// Round 15
// 1838.484 us; speedup vs baseline: 1.5214x; 1.5214x over previous
//
#include <hip/hip_runtime.h>
#include <stdint.h>

#define Bn 128
#define Tn 256
#define En 300
#define Hn 1024
#define PADIDX 1
#define NBLK 256         // 2 groups x 128 col-blocks
#define NROT 16          // h buffer rotation depth (fresh address per step)

typedef short s16x8 __attribute__((ext_vector_type(8)));
typedef float f32x4 __attribute__((ext_vector_type(4)));
typedef unsigned int u32;
typedef u32 u32x4 __attribute__((ext_vector_type(4)));

#define LDQ32(p) __hip_atomic_load((p), __ATOMIC_RELAXED, __HIP_MEMORY_SCOPE_SYSTEM)
#define ST32(p, v) __hip_atomic_store((p), (v), __ATOMIC_RELAXED, __HIP_MEMORY_SCOPE_SYSTEM)

__device__ __forceinline__ unsigned short f2bf(float f) {
  u32 u = __builtin_bit_cast(u32, f);
  u32 r = (u + 0x7fffu + ((u >> 16) & 1u)) >> 16;  // RNE
  return (unsigned short)r;
}
__device__ __forceinline__ float bf2f(unsigned short h) {
  u32 u = ((u32)h) << 16;
  return __builtin_bit_cast(float, u);
}
__device__ __forceinline__ float sigmoidf_(float x) { return 1.f / (1.f + __expf(-x)); }
__device__ __forceinline__ float tanhf_(float x) { return 1.f - 2.f / (__expf(2.f * x) + 1.f); }

// h load: sc0 only -> bypass L1, cache in XCD L2. NOT valid until manual s_waitcnt.
__device__ __forceinline__ u32x4 ldg_sc0_x4(const u32* p) {
  u32x4 r;
  asm volatile("global_load_dwordx4 %0, %1, off sc0" : "=v"(r) : "v"(p));
  return r;
}
#define WAITV24 do { asm volatile("s_waitcnt vmcnt(24)" ::: "memory"); \
                     __builtin_amdgcn_sched_barrier(0); } while (0)
#define WAITV16 do { asm volatile("s_waitcnt vmcnt(16)" ::: "memory"); \
                     __builtin_amdgcn_sched_barrier(0); } while (0)
#define WAITV8  do { asm volatile("s_waitcnt vmcnt(8)" ::: "memory");  \
                     __builtin_amdgcn_sched_barrier(0); } while (0)
#define WAITV0  do { asm volatile("s_waitcnt vmcnt(0)" ::: "memory");  \
                     __builtin_amdgcn_sched_barrier(0); } while (0)

// lane holds gate `gate` value v for its (b,unit); recover all 4 gates via shfl
__device__ __forceinline__ float gate_update(float pre, float& c, int gate) {
  float v = (gate == 2) ? tanhf_(pre) : sigmoidf_(pre);
  float vB = __shfl_xor(v, 4);
  float vC = __shfl_xor(v, 8);
  float vD = __shfl_xor(vB, 8);
  float i_ = (gate & 2) ? ((gate & 1) ? vD : vC) : ((gate & 1) ? vB : v);
  float f_ = (gate & 2) ? ((gate & 1) ? vC : vD) : ((gate & 1) ? v : vB);
  float g_ = (gate & 2) ? ((gate & 1) ? vB : v) : ((gate & 1) ? vD : vC);
  float o_ = (gate & 2) ? ((gate & 1) ? v : vB) : ((gate & 1) ? vC : vD);
  float cn = f_ * c + i_ * g_;
  c = cn;
  return o_ * tanhf_(cn);
}

// ---------------- K0: lengths -> tstar / padflag ----------------
__global__ void prep_kernel(const int* __restrict__ x, int* __restrict__ tstar,
                            int* __restrict__ padflag) {
  int b = threadIdx.x;
  if (b < Bn) {
    int len = 0;
    for (int t = 0; t < Tn; ++t) len += (x[b * Tn + t] != PADIDX) ? 1 : 0;
    int ts = (len > 0) ? (len - 1) : (Tn - 1);  // jax wraps index -1
    tstar[b] = ts;
    padflag[b] = (x[b * Tn + ts] == PADIDX) ? 1 : 0;
  }
}

// ---------------- K1: embedding gather, A-fragment-linear (R5/R10-verified) -----
// inp2[((t*8 + rg)*10 + ks)*64 + l][8] ; rg = group*4+wv ; b = rg*16+(l&15) ;
// k = ks*32 + (l>>4)*8 + jj ; zero-padded past 300.
__global__ void gather2_kernel(const int* __restrict__ x, const float* __restrict__ embed,
                               unsigned short* __restrict__ inp2) {
  int idx = blockIdx.x * 256 + threadIdx.x;  // total 256*8*10*512 = 10,485,760
  int jj = idx & 7;
  int tmp = idx >> 3;
  int l = tmp & 63; tmp >>= 6;
  int ks = tmp % 10; tmp /= 10;
  int rg = tmp & 7;
  int t = tmp >> 3;
  int b = rg * 16 + (l & 15);
  int k = ks * 32 + (l >> 4) * 8 + jj;
  int tok = x[b * Tn + t];
  float v = (k < En) ? embed[(size_t)tok * En + k] : 0.f;
  inp2[idx] = f2bf(v);
}

// ---------------- K1b: W_ih -> bf16, B-fragment-linear keyed by (cb, ct, ks) ---
// wih3[((cb*2+ct)*10+ks)*512 + l*8 + jj]; row = ((l&15)>>2)*Hn + cb*8 + ((l&15)&3)
// + ct*4; k = ks*32 + (l>>4)*8 + jj ; zero-padded past 300.  (R14-verified)
__global__ void wih3_kernel(const float* __restrict__ Wih, unsigned short* __restrict__ wih3) {
  int idx = blockIdx.x * 256 + threadIdx.x;  // total 128*2*10*512 = 1,310,720
  int jj = idx & 7;
  int tmp = idx >> 3;
  int l = tmp & 63; tmp >>= 6;
  int ks = tmp % 10; tmp /= 10;     // tmp = cb*2 + ct
  int ct = tmp & 1, cb = tmp >> 1;
  int c16 = l & 15;
  int grow = (c16 >> 2) * Hn + cb * 8 + (c16 & 3) + ct * 4;
  int k = ks * 32 + (l >> 4) * 8 + jj;
  float v = (k < En) ? Wih[(size_t)grow * En + k] : 0.f;
  wih3[idx] = f2bf(v);
}

// ---------------- K2: persistent LSTM scan (K-SPLIT recurrent) ----------------
// 256 blocks x 256 thr (4 waves). group = bid>>7 (64 batches); 128 col-blocks/group,
// each 8 hidden units (32 gate cols). W_hh hi/lo in 128 KB 0-conflict fragment-
// linear LDS. NEW: wave w computes the recurrent GEMM for K-slice [w*256,(w+1)*256)
// over ALL 64 batches -> each wave reads only ITS 32 KB W quarter (LDS W traffic
// 512->128 reads/CU/step). Partials exchanged via 24 KB LDS (12 contiguous 2 KB
// col-major areas, conflict-free), one extra barrier. W_ih from global wih3
// (L2-hot, all 4 waves load in parallel). h single bf16 block-major, rotation
// NROT=16, stores ST32 sc0sc1, loads sc0, R10 barrier protocol — all R13-proven.
__global__ __launch_bounds__(256, 1) void lstm_scan(
    const float* __restrict__ Whh, const unsigned short* __restrict__ wih3,
    const float* __restrict__ bih, const float* __restrict__ bhh,
    const unsigned short* __restrict__ inp2, const int* __restrict__ tstar,
    const int* __restrict__ padflag, unsigned short* __restrict__ h_pk,
    float* __restrict__ hsel, u32* __restrict__ flags) {
  // W elem index i = ks*1024 + ct*512 + lq*128 + lr*8 + j (contig per (ks,ct) read)
  __shared__ unsigned short lds_hi[32768];   // 64 KB  W_hh hi
  __shared__ unsigned short lds_lo[32768];   // 64 KB  W_hh lo
  __shared__ float red[12 * 512];            // 24 KB  partial exchange [q][slot]

  const int bid = blockIdx.x;
  const int group = bid >> 7;              // 0: batches 0-63, 1: batches 64-127
  const int cb = bid & 127;                // col-block within group
  const int u0 = cb * 8;                   // 8 hidden units per block
  const int tid = threadIdx.x;

  // --- W_hh slice -> LDS hi/lo, fragment-linear ---
  for (int i = tid; i < 32768; i += 256) {
    int j = i & 7, lr = (i >> 3) & 15, lq = (i >> 7) & 3, ct = (i >> 9) & 1, ks = i >> 10;
    int col = (lr >> 2) * Hn + u0 + (lr & 3) + ct * 4;
    int k = ks * 32 + lq * 8 + j;
    float w = Whh[(size_t)col * Hn + k];
    unsigned short hi = f2bf(w);
    lds_hi[i] = hi;
    lds_lo[i] = f2bf(w - bf2f(hi));
  }
  __syncthreads();

  const int wv = tid >> 6, l = tid & 63;
  const int lr = l & 15;                    // col in tile / A batch-row
  const int lq = l >> 4;                    // quadrant
  const int usub = lr & 3, gate = lr >> 2;
  const int b0w = group * 64 + wv * 16;     // wave's OWNED 16 batch rows (gates)
  const int col0 = gate * Hn + u0 + usub;   // ct=0 gate column; ct=1 is col0+4
  const float bias0 = bih[col0] + bhh[col0];
  const float bias1 = bih[col0 + 4] + bhh[col0 + 4];
  const u32 lfrag = (u32)(lq * 256 + lr * 16);   // per-lane byte in 1 KB fragment
  u32* const fg = flags + (group << 7);     // group's 128 per-block flags
  const unsigned short* wB = wih3 + (size_t)cb * 10240 + l * 8;  // +ct*5120+ks*512

  int tsr[4], pfr[4];
#pragma unroll
  for (int r = 0; r < 4; ++r) {
    int b = b0w + lq * 4 + r;
    tsr[r] = tstar[b];
    pfr[r] = padflag[b];
  }
  float creg0[4] = {0.f, 0.f, 0.f, 0.f};
  float creg1[4] = {0.f, 0.f, 0.f, 0.f};

  const char* base_hi = (const char*)lds_hi;
  const char* base_lo = (const char*)lds_lo;
  char* const redc = (char*)red;

  u32x4 qa[8][4];  // h prefetch: [ks_loc][bq], 16B each (single bf16)

// h block-major (shorts): addr = cb'*1024 + b*8 ; cb' = k/8 = wv*32 + ks*4 + lq
#define ISSUE_K(KS)                                                              \
  _Pragma("unroll") for (int bq = 0; bq < 4; ++bq) {                             \
    qa[KS][bq] = ldg_sc0_x4((const u32*)(hbase + (KS) * 4096 + bq * 128));       \
  }
#define BODY_K(KS)                                                              \
  {                                                                             \
    u32 ob = (u32)(wv * 8 + (KS)) * 2048 + lfrag;                               \
    s16x8 bh0 = *(const s16x8*)(base_hi + ob);                                  \
    s16x8 bl0 = *(const s16x8*)(base_lo + ob);                                  \
    s16x8 bh1 = *(const s16x8*)(base_hi + ob + 1024);                           \
    s16x8 bl1 = *(const s16x8*)(base_lo + ob + 1024);                           \
    _Pragma("unroll") for (int bq = 0; bq < 4; ++bq) {                          \
      s16x8 a = __builtin_bit_cast(s16x8, qa[KS][bq]);                          \
      accq[bq][0] = __builtin_amdgcn_mfma_f32_16x16x32_bf16(a, bh0, accq[bq][0], 0, 0, 0); \
      accq[bq][0] = __builtin_amdgcn_mfma_f32_16x16x32_bf16(a, bl0, accq[bq][0], 0, 0, 0); \
      accq[bq][1] = __builtin_amdgcn_mfma_f32_16x16x32_bf16(a, bh1, accq[bq][1], 0, 0, 0); \
      accq[bq][1] = __builtin_amdgcn_mfma_f32_16x16x32_bf16(a, bl1, accq[bq][1], 0, 0, 0); \
    }                                                                           \
  }

  for (int t = 0; t < Tn; ++t) {
    // ---- x-projection for OWNED 16 batches (h-independent; W_ih from global) ----
    f32x4 accx0 = {bias0, bias0, bias0, bias0};
    f32x4 accx1 = {bias1, bias1, bias1, bias1};
    const unsigned short* ipA =
        inp2 + ((size_t)(t * 8 + (group * 4 + wv)) * 10) * 512 + l * 8;
#pragma unroll
    for (int ks = 0; ks < 10; ++ks) {
      s16x8 a = *(const s16x8*)(ipA + ks * 512);
      s16x8 b0 = *(const s16x8*)(wB + ks * 512);
      s16x8 b1 = *(const s16x8*)(wB + 5120 + ks * 512);
      accx0 = __builtin_amdgcn_mfma_f32_16x16x32_bf16(a, b0, accx0, 0, 0, 0);
      accx1 = __builtin_amdgcn_mfma_f32_16x16x32_bf16(a, b1, accx1, 0, 0, 0);
    }

    // ---- release: wave 0 polls the 128 flags; others sleep at the barrier ----
    if (t) {
      if (wv == 0) {
        u32 spins = 0;
        for (;;) {
          u32 f0 = LDQ32(fg + l);
          u32 f1 = LDQ32(fg + 64 + l);
          if (__ballot((f0 >= (u32)t) & (f1 >= (u32)t)) == ~0ull) break;
          __builtin_amdgcn_s_sleep(1);
          if (++spins > 400000u) break;  // watchdog: dead unless deadlock
        }
      }
      __syncthreads();                   // B1
    }
    WAITV0;  // clean vmcnt before counted prefetch chain

    // ---- recurrent K-slice [wv*256, wv*256+256) over ALL 64 batches ----
    f32x4 accq[4][2];
#pragma unroll
    for (int bq = 0; bq < 4; ++bq) {
      accq[bq][0] = (f32x4){0.f, 0.f, 0.f, 0.f};
      accq[bq][1] = (f32x4){0.f, 0.f, 0.f, 0.f};
    }
    const unsigned short* hbase = h_pk + (size_t)(t & (NROT - 1)) * (Bn * Hn) +
                                  (u32)((wv * 32 + lq) * 1024 + (group * 64 + lr) * 8);
    ISSUE_K(0) ISSUE_K(1) ISSUE_K(2) ISSUE_K(3)
    ISSUE_K(4) ISSUE_K(5) ISSUE_K(6) ISSUE_K(7)
    WAITV24; BODY_K(0) BODY_K(1)
    WAITV16; BODY_K(2) BODY_K(3)
    WAITV8;  BODY_K(4) BODY_K(5)
    WAITV0;  BODY_K(6) BODY_K(7)

    // ---- partial exchange: write 3 non-owned quarters (col-major, contig) ----
    f32x4 own0, own1;
#pragma unroll
    for (int bq = 0; bq < 4; ++bq) {
      if (bq == wv) {
        own0 = accq[bq][0];
        own1 = accq[bq][1];
      } else {
        u32 slotw = (u32)(wv - (wv > bq ? 1 : 0));
        u32 basew = ((u32)bq * 3 + slotw) * 2048 + (u32)(lr * 64 + lq * 16);
        *(f32x4*)(redc + basew) = accq[bq][0];
        *(f32x4*)(redc + basew + 1024) = accq[bq][1];
      }
    }
    __syncthreads();                     // B_red
    f32x4 tot0 = accx0 + own0;
    f32x4 tot1 = accx1 + own1;
#pragma unroll
    for (int s = 0; s < 3; ++s) {
      u32 baser = ((u32)wv * 3 + (u32)s) * 2048 + (u32)(lr * 64 + lq * 16);
      tot0 += *(const f32x4*)(redc + baser);
      tot1 += *(const f32x4*)(redc + baser + 1024);
    }

    // ---- gates + state update for OWNED 16 batches; bf16 h pair-packed ----
    unsigned short* const hout =
        h_pk + (size_t)((t + 1) & (NROT - 1)) * (Bn * Hn);
#pragma unroll
    for (int r = 0; r < 4; ++r) {
      float h0 = gate_update(tot0[r], creg0[r], gate);
      float h1 = gate_update(tot1[r], creg1[r], gate);
      u32 h0h = (u32)f2bf(h0);
      u32 h1h = (u32)f2bf(h1);
      u32 n0 = (u32)__shfl_xor((int)h0h, 1);   // neighbor usub^1 (convergent)
      u32 n1 = (u32)__shfl_xor((int)h1h, 1);
      if (gate == 0) {
        int b = b0w + lq * 4 + r;
        if ((usub & 1) == 0) {
          unsigned short* slice = hout + (u32)(cb * 1024 + b * 8);
          ST32((u32*)(slice + usub), h0h | (n0 << 16));
          ST32((u32*)(slice + usub + 4), h1h | (n1 << 16));
        }
        if (t == tsr[r]) {
          hsel[(size_t)b * Hn + u0 + usub] = pfr[r] ? 0.f : h0;
          hsel[(size_t)b * Hn + u0 + usub + 4] = pfr[r] ? 0.f : h1;
        }
      }
    }

    // ---- arrival: barrier (drains each wave's vmcnt), publish flag ----
    __syncthreads();                     // B2
    if (tid == 0) ST32(fg + cb, (u32)(t + 1));
    // every 8 steps: invalidate local L2/L1 h copies; guarantees no stale h line
    // survives to the address's reuse at t+16
    if ((t & 7) == 7) __builtin_amdgcn_fence(__ATOMIC_ACQUIRE, "agent");
  }
#undef ISSUE_K
#undef BODY_K
}

// ---------------- K3: out[b][o] = hsel[b]·W_out[o] + b_out[o] ----------------
__global__ void head_kernel(const float* __restrict__ hsel, const float* __restrict__ Wout,
                            const float* __restrict__ bout, float* __restrict__ out) {
  int b = blockIdx.x;
  int l = threadIdx.x;  // 64 threads
  float s0 = 0.f, s1 = 0.f, s2 = 0.f;
  for (int j = l; j < Hn; j += 64) {
    float h = hsel[(size_t)b * Hn + j];
    s0 += h * Wout[j];
    s1 += h * Wout[Hn + j];
    s2 += h * Wout[2 * Hn + j];
  }
#pragma unroll
  for (int m = 32; m; m >>= 1) {
    s0 += __shfl_xor(s0, m);
    s1 += __shfl_xor(s1, m);
    s2 += __shfl_xor(s2, m);
  }
  if (l == 0) {
    out[b * 3 + 0] = s0 + bout[0];
    out[b * 3 + 1] = s1 + bout[1];
    out[b * 3 + 2] = s2 + bout[2];
  }
}

extern "C" void kernel_launch(void* const* d_in, const int* in_sizes, int n_in,
                              void* d_out, int out_size, void* d_ws, size_t ws_size,
                              hipStream_t stream) {
  const int* x = (const int*)d_in[0];
  const float* embed = (const float*)d_in[1];
  const float* Wih = (const float*)d_in[2];
  const float* Whh = (const float*)d_in[3];
  const float* bih = (const float*)d_in[4];
  const float* bhh = (const float*)d_in[5];
  const float* Wout = (const float*)d_in[6];
  const float* bout = (const float*)d_in[7];
  float* out = (float*)d_out;

  // ws layout
  const size_t INP2_BYTES = (size_t)Tn * 8 * 10 * 512 * 2;   // 20,971,520
  const size_t WIH3_BYTES = (size_t)128 * 2 * 10 * 512 * 2;  //  2,621,440
  const size_t HPK_BYTES = (size_t)NROT * Bn * Hn * 2;       //  4,194,304
  const size_t HSEL_BYTES = (size_t)Bn * Hn * 4;             //    524,288
  char* p = (char*)d_ws;
  unsigned short* inp2 = (unsigned short*)p;            p += INP2_BYTES;
  unsigned short* wih3 = (unsigned short*)p;            p += WIH3_BYTES;
  unsigned short* h_pk = (unsigned short*)p;            p += HPK_BYTES;
  float* hsel = (float*)p;                              p += HSEL_BYTES;
  int* tstar = (int*)p;                                 p += 512;
  int* padflag = (int*)p;                               p += 512;
  u32* flags = (u32*)p;                                 p += 1024;

  // per-launch init: h(0) = 0 (rotation slot 0), flags = 0 (self-contained replay)
  hipMemsetAsync(h_pk, 0, (size_t)Bn * Hn * 2, stream);
  hipMemsetAsync(flags, 0, 1024, stream);

  prep_kernel<<<1, 128, 0, stream>>>(x, tstar, padflag);
  gather2_kernel<<<40960, 256, 0, stream>>>(x, embed, inp2);
  wih3_kernel<<<5120, 256, 0, stream>>>(Wih, wih3);
  lstm_scan<<<NBLK, 256, 0, stream>>>(Whh, wih3, bih, bhh, inp2, tstar, padflag,
                                      h_pk, hsel, flags);
  head_kernel<<<Bn, 64, 0, stream>>>(hsel, Wout, bout, out);
}

// Round 17
// 1745.296 us; speedup vs baseline: 1.6026x; 1.0534x over previous
//
#include <hip/hip_runtime.h>
#include <stdint.h>

#define Bn 128
#define Tn 256
#define En 300
#define Hn 1024
#define PADIDX 1
#define NBLK 256         // 2 groups x 128 col-blocks
#define NROT 16          // h buffer rotation depth (fresh address per step)

typedef short s16x8 __attribute__((ext_vector_type(8)));
typedef float f32x4 __attribute__((ext_vector_type(4)));
typedef unsigned int u32;
typedef u32 u32x4 __attribute__((ext_vector_type(4)));

#define LDQ32(p) __hip_atomic_load((p), __ATOMIC_RELAXED, __HIP_MEMORY_SCOPE_SYSTEM)
#define ST32(p, v) __hip_atomic_store((p), (v), __ATOMIC_RELAXED, __HIP_MEMORY_SCOPE_SYSTEM)

__device__ __forceinline__ unsigned short f2bf(float f) {
  u32 u = __builtin_bit_cast(u32, f);
  u32 r = (u + 0x7fffu + ((u >> 16) & 1u)) >> 16;  // RNE
  return (unsigned short)r;
}
__device__ __forceinline__ float bf2f(unsigned short h) {
  u32 u = ((u32)h) << 16;
  return __builtin_bit_cast(float, u);
}
__device__ __forceinline__ float sigmoidf_(float x) { return 1.f / (1.f + __expf(-x)); }
__device__ __forceinline__ float tanhf_(float x) { return 1.f - 2.f / (__expf(2.f * x) + 1.f); }

// h load: sc0 only -> bypass L1, cache in XCD L2. NOT valid until manual s_waitcnt.
__device__ __forceinline__ u32x4 ldg_sc0_x4(const u32* p) {
  u32x4 r;
  asm volatile("global_load_dwordx4 %0, %1, off sc0" : "=v"(r) : "v"(p));
  return r;
}
#define WAITV24 do { asm volatile("s_waitcnt vmcnt(24)" ::: "memory"); \
                     __builtin_amdgcn_sched_barrier(0); } while (0)
#define WAITV16 do { asm volatile("s_waitcnt vmcnt(16)" ::: "memory"); \
                     __builtin_amdgcn_sched_barrier(0); } while (0)
#define WAITV8  do { asm volatile("s_waitcnt vmcnt(8)" ::: "memory");  \
                     __builtin_amdgcn_sched_barrier(0); } while (0)
#define WAITV0  do { asm volatile("s_waitcnt vmcnt(0)" ::: "memory");  \
                     __builtin_amdgcn_sched_barrier(0); } while (0)

// lane holds gate `gate` value v for its (b,unit); recover all 4 gates via shfl
__device__ __forceinline__ float gate_update(float pre, float& c, int gate) {
  float v = (gate == 2) ? tanhf_(pre) : sigmoidf_(pre);
  float vB = __shfl_xor(v, 4);
  float vC = __shfl_xor(v, 8);
  float vD = __shfl_xor(vB, 8);
  float i_ = (gate & 2) ? ((gate & 1) ? vD : vC) : ((gate & 1) ? vB : v);
  float f_ = (gate & 2) ? ((gate & 1) ? vC : vD) : ((gate & 1) ? v : vB);
  float g_ = (gate & 2) ? ((gate & 1) ? vB : v) : ((gate & 1) ? vD : vC);
  float o_ = (gate & 2) ? ((gate & 1) ? v : vB) : ((gate & 1) ? vC : vD);
  float cn = f_ * c + i_ * g_;
  c = cn;
  return o_ * tanhf_(cn);
}

// ---------------- K0: lengths -> tstar / padflag ----------------
__global__ void prep_kernel(const int* __restrict__ x, int* __restrict__ tstar,
                            int* __restrict__ padflag) {
  int b = threadIdx.x;
  if (b < Bn) {
    int len = 0;
    for (int t = 0; t < Tn; ++t) len += (x[b * Tn + t] != PADIDX) ? 1 : 0;
    int ts = (len > 0) ? (len - 1) : (Tn - 1);  // jax wraps index -1
    tstar[b] = ts;
    padflag[b] = (x[b * Tn + ts] == PADIDX) ? 1 : 0;
  }
}

// ---------------- K1: embedding gather, A-fragment-linear (R5/R10-verified) -----
// inp2[((t*8 + rg)*10 + ks)*64 + l][8] ; rg = group*4+wv ; b = rg*16+(l&15) ;
// k = ks*32 + (l>>4)*8 + jj ; zero-padded past 300.
__global__ void gather2_kernel(const int* __restrict__ x, const float* __restrict__ embed,
                               unsigned short* __restrict__ inp2) {
  int idx = blockIdx.x * 256 + threadIdx.x;  // total 256*8*10*512 = 10,485,760
  int jj = idx & 7;
  int tmp = idx >> 3;
  int l = tmp & 63; tmp >>= 6;
  int ks = tmp % 10; tmp /= 10;
  int rg = tmp & 7;
  int t = tmp >> 3;
  int b = rg * 16 + (l & 15);
  int k = ks * 32 + (l >> 4) * 8 + jj;
  int tok = x[b * Tn + t];
  float v = (k < En) ? embed[(size_t)tok * En + k] : 0.f;
  inp2[idx] = f2bf(v);
}

// ---------------- K1b: W_ih -> bf16, B-fragment-linear keyed by (cb, ct, ks) ---
// wih3[((cb*2+ct)*10+ks)*512 + l*8 + jj]; row = ((l&15)>>2)*Hn + cb*8 + ((l&15)&3)
// + ct*4; k = ks*32 + (l>>4)*8 + jj ; zero-padded past 300.  (R14/R15-verified)
__global__ void wih3_kernel(const float* __restrict__ Wih, unsigned short* __restrict__ wih3) {
  int idx = blockIdx.x * 256 + threadIdx.x;  // total 128*2*10*512 = 1,310,720
  int jj = idx & 7;
  int tmp = idx >> 3;
  int l = tmp & 63; tmp >>= 6;
  int ks = tmp % 10; tmp /= 10;     // tmp = cb*2 + ct
  int ct = tmp & 1, cb = tmp >> 1;
  int c16 = l & 15;
  int grow = (c16 >> 2) * Hn + cb * 8 + (c16 & 3) + ct * 4;
  int k = ks * 32 + (l >> 4) * 8 + jj;
  float v = (k < En) ? Wih[(size_t)grow * En + k] : 0.f;
  wih3[idx] = f2bf(v);
}

// ---------------- K2: persistent LSTM scan (K-split, single-bf16 W_hh) ---------
// R15 STRUCTURE VERBATIM (B2 __syncthreads + tid0 publish — the counter-publish
// variant livelocked twice, R11/R16, and is abandoned). ONLY change vs R15:
// W_hh stored as SINGLE bf16 (64 KB LDS; evidence: R12->R13 dropped h_lo·W_hi —
// identical |h||W|·2^-9 magnitude class — with exactly zero absmax change).
// Recurrent = 2 MFMA + 2 ds_read per ks (was 4+4). K-split over waves, partial
// exchange via 24 KB LDS, W_ih from global wih3, h single bf16 block-major,
// rotation NROT=16, stores ST32 sc0sc1, loads sc0, wave-0 flag poll.
__global__ __launch_bounds__(256, 1) void lstm_scan(
    const float* __restrict__ Whh, const unsigned short* __restrict__ wih3,
    const float* __restrict__ bih, const float* __restrict__ bhh,
    const unsigned short* __restrict__ inp2, const int* __restrict__ tstar,
    const int* __restrict__ padflag, unsigned short* __restrict__ h_pk,
    float* __restrict__ hsel, u32* __restrict__ flags) {
  // W elem index i = ks*1024 + ct*512 + lq*128 + lr*8 + j (contig per (ks,ct) read)
  __shared__ unsigned short lds_hi[32768];   // 64 KB  W_hh (single bf16)
  __shared__ float red[12 * 512];            // 24 KB  partial exchange [q][slot]

  const int bid = blockIdx.x;
  const int group = bid >> 7;              // 0: batches 0-63, 1: batches 64-127
  const int cb = bid & 127;                // col-block within group
  const int u0 = cb * 8;                   // 8 hidden units per block
  const int tid = threadIdx.x;

  // --- W_hh slice -> LDS (single bf16), fragment-linear ---
  for (int i = tid; i < 32768; i += 256) {
    int j = i & 7, lr = (i >> 3) & 15, lq = (i >> 7) & 3, ct = (i >> 9) & 1, ks = i >> 10;
    int col = (lr >> 2) * Hn + u0 + (lr & 3) + ct * 4;
    int k = ks * 32 + lq * 8 + j;
    lds_hi[i] = f2bf(Whh[(size_t)col * Hn + k]);
  }
  __syncthreads();

  const int wv = tid >> 6, l = tid & 63;
  const int lr = l & 15;                    // col in tile / A batch-row
  const int lq = l >> 4;                    // quadrant
  const int usub = lr & 3, gate = lr >> 2;
  const int b0w = group * 64 + wv * 16;     // wave's OWNED 16 batch rows (gates)
  const int col0 = gate * Hn + u0 + usub;   // ct=0 gate column; ct=1 is col0+4
  const float bias0 = bih[col0] + bhh[col0];
  const float bias1 = bih[col0 + 4] + bhh[col0 + 4];
  const u32 lfrag = (u32)(lq * 256 + lr * 16);   // per-lane byte in 1 KB fragment
  u32* const fg = flags + (group << 7);     // group's 128 per-block flags
  const unsigned short* wB = wih3 + (size_t)cb * 10240 + l * 8;  // +ct*5120+ks*512

  int tsr[4], pfr[4];
#pragma unroll
  for (int r = 0; r < 4; ++r) {
    int b = b0w + lq * 4 + r;
    tsr[r] = tstar[b];
    pfr[r] = padflag[b];
  }
  float creg0[4] = {0.f, 0.f, 0.f, 0.f};
  float creg1[4] = {0.f, 0.f, 0.f, 0.f};

  const char* base_hi = (const char*)lds_hi;
  char* const redc = (char*)red;

  u32x4 qa[8][4];  // h prefetch: [ks_loc][bq], 16B each (single bf16)

// h block-major (shorts): addr = cb'*1024 + b*8 ; cb' = k/8 = wv*32 + ks*4 + lq
#define ISSUE_K(KS)                                                              \
  _Pragma("unroll") for (int bq = 0; bq < 4; ++bq) {                             \
    qa[KS][bq] = ldg_sc0_x4((const u32*)(hbase + (KS) * 4096 + bq * 128));       \
  }
#define BODY_K(KS)                                                              \
  {                                                                             \
    u32 ob = (u32)(wv * 8 + (KS)) * 2048 + lfrag;                               \
    s16x8 bh0 = *(const s16x8*)(base_hi + ob);                                  \
    s16x8 bh1 = *(const s16x8*)(base_hi + ob + 1024);                           \
    _Pragma("unroll") for (int bq = 0; bq < 4; ++bq) {                          \
      s16x8 a = __builtin_bit_cast(s16x8, qa[KS][bq]);                          \
      accq[bq][0] = __builtin_amdgcn_mfma_f32_16x16x32_bf16(a, bh0, accq[bq][0], 0, 0, 0); \
      accq[bq][1] = __builtin_amdgcn_mfma_f32_16x16x32_bf16(a, bh1, accq[bq][1], 0, 0, 0); \
    }                                                                           \
  }

  for (int t = 0; t < Tn; ++t) {
    // ---- x-projection for OWNED 16 batches (h-independent; W_ih from global) ----
    f32x4 accx0 = {bias0, bias0, bias0, bias0};
    f32x4 accx1 = {bias1, bias1, bias1, bias1};
    const unsigned short* ipA =
        inp2 + ((size_t)(t * 8 + (group * 4 + wv)) * 10) * 512 + l * 8;
#pragma unroll
    for (int ks = 0; ks < 10; ++ks) {
      s16x8 a = *(const s16x8*)(ipA + ks * 512);
      s16x8 b0 = *(const s16x8*)(wB + ks * 512);
      s16x8 b1 = *(const s16x8*)(wB + 5120 + ks * 512);
      accx0 = __builtin_amdgcn_mfma_f32_16x16x32_bf16(a, b0, accx0, 0, 0, 0);
      accx1 = __builtin_amdgcn_mfma_f32_16x16x32_bf16(a, b1, accx1, 0, 0, 0);
    }

    // ---- release: wave 0 polls the 128 flags; others sleep at the barrier ----
    if (t) {
      if (wv == 0) {
        u32 spins = 0;
        for (;;) {
          u32 f0 = LDQ32(fg + l);
          u32 f1 = LDQ32(fg + 64 + l);
          if (__ballot((f0 >= (u32)t) & (f1 >= (u32)t)) == ~0ull) break;
          __builtin_amdgcn_s_sleep(1);
          if (++spins > 400000u) break;  // watchdog: dead unless deadlock
        }
      }
      __syncthreads();                   // B1
    }
    WAITV0;  // clean vmcnt before counted prefetch chain

    // ---- recurrent K-slice [wv*256, wv*256+256) over ALL 64 batches ----
    f32x4 accq[4][2];
#pragma unroll
    for (int bq = 0; bq < 4; ++bq) {
      accq[bq][0] = (f32x4){0.f, 0.f, 0.f, 0.f};
      accq[bq][1] = (f32x4){0.f, 0.f, 0.f, 0.f};
    }
    const unsigned short* hbase = h_pk + (size_t)(t & (NROT - 1)) * (Bn * Hn) +
                                  (u32)((wv * 32 + lq) * 1024 + (group * 64 + lr) * 8);
    ISSUE_K(0) ISSUE_K(1) ISSUE_K(2) ISSUE_K(3)
    ISSUE_K(4) ISSUE_K(5) ISSUE_K(6) ISSUE_K(7)
    WAITV24; BODY_K(0) BODY_K(1)
    WAITV16; BODY_K(2) BODY_K(3)
    WAITV8;  BODY_K(4) BODY_K(5)
    WAITV0;  BODY_K(6) BODY_K(7)

    // ---- partial exchange: write 3 non-owned quarters (col-major, contig) ----
    f32x4 own0, own1;
#pragma unroll
    for (int bq = 0; bq < 4; ++bq) {
      if (bq == wv) {
        own0 = accq[bq][0];
        own1 = accq[bq][1];
      } else {
        u32 slotw = (u32)(wv - (wv > bq ? 1 : 0));
        u32 basew = ((u32)bq * 3 + slotw) * 2048 + (u32)(lr * 64 + lq * 16);
        *(f32x4*)(redc + basew) = accq[bq][0];
        *(f32x4*)(redc + basew + 1024) = accq[bq][1];
      }
    }
    __syncthreads();                     // B_red
    f32x4 tot0 = accx0 + own0;
    f32x4 tot1 = accx1 + own1;
#pragma unroll
    for (int s = 0; s < 3; ++s) {
      u32 baser = ((u32)wv * 3 + (u32)s) * 2048 + (u32)(lr * 64 + lq * 16);
      tot0 += *(const f32x4*)(redc + baser);
      tot1 += *(const f32x4*)(redc + baser + 1024);
    }

    // ---- gates + state update for OWNED 16 batches; bf16 h pair-packed ----
    unsigned short* const hout =
        h_pk + (size_t)((t + 1) & (NROT - 1)) * (Bn * Hn);
#pragma unroll
    for (int r = 0; r < 4; ++r) {
      float h0 = gate_update(tot0[r], creg0[r], gate);
      float h1 = gate_update(tot1[r], creg1[r], gate);
      u32 h0h = (u32)f2bf(h0);
      u32 h1h = (u32)f2bf(h1);
      u32 n0 = (u32)__shfl_xor((int)h0h, 1);   // neighbor usub^1 (convergent)
      u32 n1 = (u32)__shfl_xor((int)h1h, 1);
      if (gate == 0) {
        int b = b0w + lq * 4 + r;
        if ((usub & 1) == 0) {
          unsigned short* slice = hout + (u32)(cb * 1024 + b * 8);
          ST32((u32*)(slice + usub), h0h | (n0 << 16));
          ST32((u32*)(slice + usub + 4), h1h | (n1 << 16));
        }
        if (t == tsr[r]) {
          hsel[(size_t)b * Hn + u0 + usub] = pfr[r] ? 0.f : h0;
          hsel[(size_t)b * Hn + u0 + usub + 4] = pfr[r] ? 0.f : h1;
        }
      }
    }

    // ---- arrival: barrier (drains each wave's vmcnt), publish flag ----
    __syncthreads();                     // B2
    if (tid == 0) ST32(fg + cb, (u32)(t + 1));
    // every 8 steps: invalidate local L2/L1 h copies; guarantees no stale h line
    // survives to the address's reuse at t+16
    if ((t & 7) == 7) __builtin_amdgcn_fence(__ATOMIC_ACQUIRE, "agent");
  }
#undef ISSUE_K
#undef BODY_K
}

// ---------------- K3: out[b][o] = hsel[b]·W_out[o] + b_out[o] ----------------
__global__ void head_kernel(const float* __restrict__ hsel, const float* __restrict__ Wout,
                            const float* __restrict__ bout, float* __restrict__ out) {
  int b = blockIdx.x;
  int l = threadIdx.x;  // 64 threads
  float s0 = 0.f, s1 = 0.f, s2 = 0.f;
  for (int j = l; j < Hn; j += 64) {
    float h = hsel[(size_t)b * Hn + j];
    s0 += h * Wout[j];
    s1 += h * Wout[Hn + j];
    s2 += h * Wout[2 * Hn + j];
  }
#pragma unroll
  for (int m = 32; m; m >>= 1) {
    s0 += __shfl_xor(s0, m);
    s1 += __shfl_xor(s1, m);
    s2 += __shfl_xor(s2, m);
  }
  if (l == 0) {
    out[b * 3 + 0] = s0 + bout[0];
    out[b * 3 + 1] = s1 + bout[1];
    out[b * 3 + 2] = s2 + bout[2];
  }
}

extern "C" void kernel_launch(void* const* d_in, const int* in_sizes, int n_in,
                              void* d_out, int out_size, void* d_ws, size_t ws_size,
                              hipStream_t stream) {
  const int* x = (const int*)d_in[0];
  const float* embed = (const float*)d_in[1];
  const float* Wih = (const float*)d_in[2];
  const float* Whh = (const float*)d_in[3];
  const float* bih = (const float*)d_in[4];
  const float* bhh = (const float*)d_in[5];
  const float* Wout = (const float*)d_in[6];
  const float* bout = (const float*)d_in[7];
  float* out = (float*)d_out;

  // ws layout
  const size_t INP2_BYTES = (size_t)Tn * 8 * 10 * 512 * 2;   // 20,971,520
  const size_t WIH3_BYTES = (size_t)128 * 2 * 10 * 512 * 2;  //  2,621,440
  const size_t HPK_BYTES = (size_t)NROT * Bn * Hn * 2;       //  4,194,304
  const size_t HSEL_BYTES = (size_t)Bn * Hn * 4;             //    524,288
  char* p = (char*)d_ws;
  unsigned short* inp2 = (unsigned short*)p;            p += INP2_BYTES;
  unsigned short* wih3 = (unsigned short*)p;            p += WIH3_BYTES;
  unsigned short* h_pk = (unsigned short*)p;            p += HPK_BYTES;
  float* hsel = (float*)p;                              p += HSEL_BYTES;
  int* tstar = (int*)p;                                 p += 512;
  int* padflag = (int*)p;                               p += 512;
  u32* flags = (u32*)p;                                 p += 1024;

  // per-launch init: h(0) = 0 (rotation slot 0), flags = 0 (self-contained replay)
  hipMemsetAsync(h_pk, 0, (size_t)Bn * Hn * 2, stream);
  hipMemsetAsync(flags, 0, 1024, stream);

  prep_kernel<<<1, 128, 0, stream>>>(x, tstar, padflag);
  gather2_kernel<<<40960, 256, 0, stream>>>(x, embed, inp2);
  wih3_kernel<<<5120, 256, 0, stream>>>(Wih, wih3);
  lstm_scan<<<NBLK, 256, 0, stream>>>(Whh, wih3, bih, bhh, inp2, tstar, padflag,
                                      h_pk, hsel, flags);
  head_kernel<<<Bn, 64, 0, stream>>>(hsel, Wout, bout, out);
}

// Round 18
// 1592.949 us; speedup vs baseline: 1.7559x; 1.0956x over previous
//
#include <hip/hip_runtime.h>
#include <stdint.h>

#define Bn 128
#define Tn 256
#define En 300
#define Hn 1024
#define PADIDX 1
#define NBLK 256         // 2 groups x 128 col-blocks
#define NROT 32          // h buffer rotation depth (fresh address per step)

typedef short s16x8 __attribute__((ext_vector_type(8)));
typedef float f32x4 __attribute__((ext_vector_type(4)));
typedef unsigned int u32;
typedef u32 u32x4 __attribute__((ext_vector_type(4)));

#define LDQ32(p) __hip_atomic_load((p), __ATOMIC_RELAXED, __HIP_MEMORY_SCOPE_SYSTEM)
#define ST32(p, v) __hip_atomic_store((p), (v), __ATOMIC_RELAXED, __HIP_MEMORY_SCOPE_SYSTEM)

__device__ __forceinline__ unsigned short f2bf(float f) {
  u32 u = __builtin_bit_cast(u32, f);
  u32 r = (u + 0x7fffu + ((u >> 16) & 1u)) >> 16;  // RNE
  return (unsigned short)r;
}
__device__ __forceinline__ float bf2f(unsigned short h) {
  u32 u = ((u32)h) << 16;
  return __builtin_bit_cast(float, u);
}
__device__ __forceinline__ float sigmoidf_(float x) { return 1.f / (1.f + __expf(-x)); }
__device__ __forceinline__ float tanhf_(float x) { return 1.f - 2.f / (__expf(2.f * x) + 1.f); }

// h load: sc0 only -> bypass L1, cache in XCD L2. NOT valid until manual s_waitcnt.
__device__ __forceinline__ u32x4 ldg_sc0_x4(const u32* p) {
  u32x4 r;
  asm volatile("global_load_dwordx4 %0, %1, off sc0" : "=v"(r) : "v"(p));
  return r;
}
#define WAITV24 do { asm volatile("s_waitcnt vmcnt(24)" ::: "memory"); \
                     __builtin_amdgcn_sched_barrier(0); } while (0)
#define WAITV16 do { asm volatile("s_waitcnt vmcnt(16)" ::: "memory"); \
                     __builtin_amdgcn_sched_barrier(0); } while (0)
#define WAITV8  do { asm volatile("s_waitcnt vmcnt(8)" ::: "memory");  \
                     __builtin_amdgcn_sched_barrier(0); } while (0)
#define WAITV0  do { asm volatile("s_waitcnt vmcnt(0)" ::: "memory");  \
                     __builtin_amdgcn_sched_barrier(0); } while (0)

// lane holds gate `gate` value v for its (b,unit); recover all 4 gates via shfl
__device__ __forceinline__ float gate_update(float pre, float& c, int gate) {
  float v = (gate == 2) ? tanhf_(pre) : sigmoidf_(pre);
  float vB = __shfl_xor(v, 4);
  float vC = __shfl_xor(v, 8);
  float vD = __shfl_xor(vB, 8);
  float i_ = (gate & 2) ? ((gate & 1) ? vD : vC) : ((gate & 1) ? vB : v);
  float f_ = (gate & 2) ? ((gate & 1) ? vC : vD) : ((gate & 1) ? v : vB);
  float g_ = (gate & 2) ? ((gate & 1) ? vB : v) : ((gate & 1) ? vD : vC);
  float o_ = (gate & 2) ? ((gate & 1) ? v : vB) : ((gate & 1) ? vC : vD);
  float cn = f_ * c + i_ * g_;
  c = cn;
  return o_ * tanhf_(cn);
}

// ---------------- K0: lengths -> tstar / padflag ----------------
__global__ void prep_kernel(const int* __restrict__ x, int* __restrict__ tstar,
                            int* __restrict__ padflag) {
  int b = threadIdx.x;
  if (b < Bn) {
    int len = 0;
    for (int t = 0; t < Tn; ++t) len += (x[b * Tn + t] != PADIDX) ? 1 : 0;
    int ts = (len > 0) ? (len - 1) : (Tn - 1);  // jax wraps index -1
    tstar[b] = ts;
    padflag[b] = (x[b * Tn + ts] == PADIDX) ? 1 : 0;
  }
}

// ---------------- K1: embedding gather, A-fragment-linear (R5/R10-verified) -----
// inp2[((t*8 + rg)*10 + ks)*64 + l][8] ; rg = group*4+wv ; b = rg*16+(l&15) ;
// k = ks*32 + (l>>4)*8 + jj ; zero-padded past 300.
__global__ void gather2_kernel(const int* __restrict__ x, const float* __restrict__ embed,
                               unsigned short* __restrict__ inp2) {
  int idx = blockIdx.x * 256 + threadIdx.x;  // total 256*8*10*512 = 10,485,760
  int jj = idx & 7;
  int tmp = idx >> 3;
  int l = tmp & 63; tmp >>= 6;
  int ks = tmp % 10; tmp /= 10;
  int rg = tmp & 7;
  int t = tmp >> 3;
  int b = rg * 16 + (l & 15);
  int k = ks * 32 + (l >> 4) * 8 + jj;
  int tok = x[b * Tn + t];
  float v = (k < En) ? embed[(size_t)tok * En + k] : 0.f;
  inp2[idx] = f2bf(v);
}

// ---------------- K1b: W_ih -> bf16, B-fragment-linear keyed by (cb, ct, ks) ---
// wih3[((cb*2+ct)*10+ks)*512 + l*8 + jj]; row = ((l&15)>>2)*Hn + cb*8 + ((l&15)&3)
// + ct*4; k = ks*32 + (l>>4)*8 + jj ; zero-padded past 300.  (R14/R15-verified)
__global__ void wih3_kernel(const float* __restrict__ Wih, unsigned short* __restrict__ wih3) {
  int idx = blockIdx.x * 256 + threadIdx.x;  // total 128*2*10*512 = 1,310,720
  int jj = idx & 7;
  int tmp = idx >> 3;
  int l = tmp & 63; tmp >>= 6;
  int ks = tmp % 10; tmp /= 10;     // tmp = cb*2 + ct
  int ct = tmp & 1, cb = tmp >> 1;
  int c16 = l & 15;
  int grow = (c16 >> 2) * Hn + cb * 8 + (c16 & 3) + ct * 4;
  int k = ks * 32 + (l >> 4) * 8 + jj;
  float v = (k < En) ? Wih[(size_t)grow * En + k] : 0.f;
  wih3[idx] = f2bf(v);
}

// ---------------- K2: persistent LSTM scan (K-split, single-bf16 W_hh) ---------
// R17 structure (B2 __syncthreads + tid0 publish; counter-publish abandoned after
// R11/R16 livelocks). Changes vs R17: (1) red exchange uses the LANE-LINEAR
// bijection (area + l*16, contiguous 1 KB/wave both sides -> conflict-free like
// the W layout; identity l<->l mapping is correct because writer lane l and
// reader lane l hold the same 16x16 tile position). (2) NROT 16->32 with
// acquire-fence every 16 steps (same staleness margin: fence period = NROT/2;
// halves the wih3/inp2 L2-invalidation refetch).
__global__ __launch_bounds__(256, 1) void lstm_scan(
    const float* __restrict__ Whh, const unsigned short* __restrict__ wih3,
    const float* __restrict__ bih, const float* __restrict__ bhh,
    const unsigned short* __restrict__ inp2, const int* __restrict__ tstar,
    const int* __restrict__ padflag, unsigned short* __restrict__ h_pk,
    float* __restrict__ hsel, u32* __restrict__ flags) {
  // W elem index i = ks*1024 + ct*512 + lq*128 + lr*8 + j (contig per (ks,ct) read)
  __shared__ unsigned short lds_hi[32768];   // 64 KB  W_hh (single bf16)
  __shared__ float red[12 * 512];            // 24 KB  partial exchange [area][lane]

  const int bid = blockIdx.x;
  const int group = bid >> 7;              // 0: batches 0-63, 1: batches 64-127
  const int cb = bid & 127;                // col-block within group
  const int u0 = cb * 8;                   // 8 hidden units per block
  const int tid = threadIdx.x;

  // --- W_hh slice -> LDS (single bf16), fragment-linear ---
  for (int i = tid; i < 32768; i += 256) {
    int j = i & 7, lr = (i >> 3) & 15, lq = (i >> 7) & 3, ct = (i >> 9) & 1, ks = i >> 10;
    int col = (lr >> 2) * Hn + u0 + (lr & 3) + ct * 4;
    int k = ks * 32 + lq * 8 + j;
    lds_hi[i] = f2bf(Whh[(size_t)col * Hn + k]);
  }
  __syncthreads();

  const int wv = tid >> 6, l = tid & 63;
  const int lr = l & 15;                    // col in tile / A batch-row
  const int lq = l >> 4;                    // quadrant
  const int usub = lr & 3, gate = lr >> 2;
  const int b0w = group * 64 + wv * 16;     // wave's OWNED 16 batch rows (gates)
  const int col0 = gate * Hn + u0 + usub;   // ct=0 gate column; ct=1 is col0+4
  const float bias0 = bih[col0] + bhh[col0];
  const float bias1 = bih[col0 + 4] + bhh[col0 + 4];
  const u32 lfrag = (u32)(lq * 256 + lr * 16);   // per-lane byte in 1 KB fragment
  const u32 lred = (u32)(l * 16);                // lane-linear byte in 1 KB area
  u32* const fg = flags + (group << 7);     // group's 128 per-block flags
  const unsigned short* wB = wih3 + (size_t)cb * 10240 + l * 8;  // +ct*5120+ks*512

  int tsr[4], pfr[4];
#pragma unroll
  for (int r = 0; r < 4; ++r) {
    int b = b0w + lq * 4 + r;
    tsr[r] = tstar[b];
    pfr[r] = padflag[b];
  }
  float creg0[4] = {0.f, 0.f, 0.f, 0.f};
  float creg1[4] = {0.f, 0.f, 0.f, 0.f};

  const char* base_hi = (const char*)lds_hi;
  char* const redc = (char*)red;

  u32x4 qa[8][4];  // h prefetch: [ks_loc][bq], 16B each (single bf16)

// h block-major (shorts): addr = cb'*1024 + b*8 ; cb' = k/8 = wv*32 + ks*4 + lq
#define ISSUE_K(KS)                                                              \
  _Pragma("unroll") for (int bq = 0; bq < 4; ++bq) {                             \
    qa[KS][bq] = ldg_sc0_x4((const u32*)(hbase + (KS) * 4096 + bq * 128));       \
  }
#define BODY_K(KS)                                                              \
  {                                                                             \
    u32 ob = (u32)(wv * 8 + (KS)) * 2048 + lfrag;                               \
    s16x8 bh0 = *(const s16x8*)(base_hi + ob);                                  \
    s16x8 bh1 = *(const s16x8*)(base_hi + ob + 1024);                           \
    _Pragma("unroll") for (int bq = 0; bq < 4; ++bq) {                          \
      s16x8 a = __builtin_bit_cast(s16x8, qa[KS][bq]);                          \
      accq[bq][0] = __builtin_amdgcn_mfma_f32_16x16x32_bf16(a, bh0, accq[bq][0], 0, 0, 0); \
      accq[bq][1] = __builtin_amdgcn_mfma_f32_16x16x32_bf16(a, bh1, accq[bq][1], 0, 0, 0); \
    }                                                                           \
  }

  for (int t = 0; t < Tn; ++t) {
    // ---- x-projection for OWNED 16 batches (h-independent; W_ih from global) ----
    f32x4 accx0 = {bias0, bias0, bias0, bias0};
    f32x4 accx1 = {bias1, bias1, bias1, bias1};
    const unsigned short* ipA =
        inp2 + ((size_t)(t * 8 + (group * 4 + wv)) * 10) * 512 + l * 8;
#pragma unroll
    for (int ks = 0; ks < 10; ++ks) {
      s16x8 a = *(const s16x8*)(ipA + ks * 512);
      s16x8 b0 = *(const s16x8*)(wB + ks * 512);
      s16x8 b1 = *(const s16x8*)(wB + 5120 + ks * 512);
      accx0 = __builtin_amdgcn_mfma_f32_16x16x32_bf16(a, b0, accx0, 0, 0, 0);
      accx1 = __builtin_amdgcn_mfma_f32_16x16x32_bf16(a, b1, accx1, 0, 0, 0);
    }

    // ---- release: wave 0 polls the 128 flags; others sleep at the barrier ----
    if (t) {
      if (wv == 0) {
        u32 spins = 0;
        for (;;) {
          u32 f0 = LDQ32(fg + l);
          u32 f1 = LDQ32(fg + 64 + l);
          if (__ballot((f0 >= (u32)t) & (f1 >= (u32)t)) == ~0ull) break;
          __builtin_amdgcn_s_sleep(1);
          if (++spins > 400000u) break;  // watchdog: dead unless deadlock
        }
      }
      __syncthreads();                   // B1
    }
    WAITV0;  // clean vmcnt before counted prefetch chain

    // ---- recurrent K-slice [wv*256, wv*256+256) over ALL 64 batches ----
    f32x4 accq[4][2];
#pragma unroll
    for (int bq = 0; bq < 4; ++bq) {
      accq[bq][0] = (f32x4){0.f, 0.f, 0.f, 0.f};
      accq[bq][1] = (f32x4){0.f, 0.f, 0.f, 0.f};
    }
    const unsigned short* hbase = h_pk + (size_t)(t & (NROT - 1)) * (Bn * Hn) +
                                  (u32)((wv * 32 + lq) * 1024 + (group * 64 + lr) * 8);
    ISSUE_K(0) ISSUE_K(1) ISSUE_K(2) ISSUE_K(3)
    ISSUE_K(4) ISSUE_K(5) ISSUE_K(6) ISSUE_K(7)
    WAITV24; BODY_K(0) BODY_K(1)
    WAITV16; BODY_K(2) BODY_K(3)
    WAITV8;  BODY_K(4) BODY_K(5)
    WAITV0;  BODY_K(6) BODY_K(7)

    // ---- partial exchange: lane-linear areas (contiguous 1 KB/wave, 0-conflict) ----
    f32x4 own0, own1;
#pragma unroll
    for (int bq = 0; bq < 4; ++bq) {
      if (bq == wv) {
        own0 = accq[bq][0];
        own1 = accq[bq][1];
      } else {
        u32 slotw = (u32)(wv - (wv > bq ? 1 : 0));
        u32 basew = ((u32)bq * 3 + slotw) * 2048 + lred;
        *(f32x4*)(redc + basew) = accq[bq][0];
        *(f32x4*)(redc + basew + 1024) = accq[bq][1];
      }
    }
    __syncthreads();                     // B_red
    f32x4 tot0 = accx0 + own0;
    f32x4 tot1 = accx1 + own1;
#pragma unroll
    for (int s = 0; s < 3; ++s) {
      u32 baser = ((u32)wv * 3 + (u32)s) * 2048 + lred;
      tot0 += *(const f32x4*)(redc + baser);
      tot1 += *(const f32x4*)(redc + baser + 1024);
    }

    // ---- gates + state update for OWNED 16 batches; bf16 h pair-packed ----
    unsigned short* const hout =
        h_pk + (size_t)((t + 1) & (NROT - 1)) * (Bn * Hn);
#pragma unroll
    for (int r = 0; r < 4; ++r) {
      float h0 = gate_update(tot0[r], creg0[r], gate);
      float h1 = gate_update(tot1[r], creg1[r], gate);
      u32 h0h = (u32)f2bf(h0);
      u32 h1h = (u32)f2bf(h1);
      u32 n0 = (u32)__shfl_xor((int)h0h, 1);   // neighbor usub^1 (convergent)
      u32 n1 = (u32)__shfl_xor((int)h1h, 1);
      if (gate == 0) {
        int b = b0w + lq * 4 + r;
        if ((usub & 1) == 0) {
          unsigned short* slice = hout + (u32)(cb * 1024 + b * 8);
          ST32((u32*)(slice + usub), h0h | (n0 << 16));
          ST32((u32*)(slice + usub + 4), h1h | (n1 << 16));
        }
        if (t == tsr[r]) {
          hsel[(size_t)b * Hn + u0 + usub] = pfr[r] ? 0.f : h0;
          hsel[(size_t)b * Hn + u0 + usub + 4] = pfr[r] ? 0.f : h1;
        }
      }
    }

    // ---- arrival: barrier (drains each wave's vmcnt), publish flag ----
    __syncthreads();                     // B2
    if (tid == 0) ST32(fg + cb, (u32)(t + 1));
    // every 16 steps: invalidate local L2/L1 h copies; with NROT=32 the fence
    // period (NROT/2) gives the same staleness margin as R13-R17's 8/16
    if ((t & 15) == 15) __builtin_amdgcn_fence(__ATOMIC_ACQUIRE, "agent");
  }
#undef ISSUE_K
#undef BODY_K
}

// ---------------- K3: out[b][o] = hsel[b]·W_out[o] + b_out[o] ----------------
__global__ void head_kernel(const float* __restrict__ hsel, const float* __restrict__ Wout,
                            const float* __restrict__ bout, float* __restrict__ out) {
  int b = blockIdx.x;
  int l = threadIdx.x;  // 64 threads
  float s0 = 0.f, s1 = 0.f, s2 = 0.f;
  for (int j = l; j < Hn; j += 64) {
    float h = hsel[(size_t)b * Hn + j];
    s0 += h * Wout[j];
    s1 += h * Wout[Hn + j];
    s2 += h * Wout[2 * Hn + j];
  }
#pragma unroll
  for (int m = 32; m; m >>= 1) {
    s0 += __shfl_xor(s0, m);
    s1 += __shfl_xor(s1, m);
    s2 += __shfl_xor(s2, m);
  }
  if (l == 0) {
    out[b * 3 + 0] = s0 + bout[0];
    out[b * 3 + 1] = s1 + bout[1];
    out[b * 3 + 2] = s2 + bout[2];
  }
}

extern "C" void kernel_launch(void* const* d_in, const int* in_sizes, int n_in,
                              void* d_out, int out_size, void* d_ws, size_t ws_size,
                              hipStream_t stream) {
  const int* x = (const int*)d_in[0];
  const float* embed = (const float*)d_in[1];
  const float* Wih = (const float*)d_in[2];
  const float* Whh = (const float*)d_in[3];
  const float* bih = (const float*)d_in[4];
  const float* bhh = (const float*)d_in[5];
  const float* Wout = (const float*)d_in[6];
  const float* bout = (const float*)d_in[7];
  float* out = (float*)d_out;

  // ws layout
  const size_t INP2_BYTES = (size_t)Tn * 8 * 10 * 512 * 2;   // 20,971,520
  const size_t WIH3_BYTES = (size_t)128 * 2 * 10 * 512 * 2;  //  2,621,440
  const size_t HPK_BYTES = (size_t)NROT * Bn * Hn * 2;       //  8,388,608
  const size_t HSEL_BYTES = (size_t)Bn * Hn * 4;             //    524,288
  char* p = (char*)d_ws;
  unsigned short* inp2 = (unsigned short*)p;            p += INP2_BYTES;
  unsigned short* wih3 = (unsigned short*)p;            p += WIH3_BYTES;
  unsigned short* h_pk = (unsigned short*)p;            p += HPK_BYTES;
  float* hsel = (float*)p;                              p += HSEL_BYTES;
  int* tstar = (int*)p;                                 p += 512;
  int* padflag = (int*)p;                               p += 512;
  u32* flags = (u32*)p;                                 p += 1024;

  // per-launch init: h(0) = 0 (rotation slot 0), flags = 0 (self-contained replay)
  hipMemsetAsync(h_pk, 0, (size_t)Bn * Hn * 2, stream);
  hipMemsetAsync(flags, 0, 1024, stream);

  prep_kernel<<<1, 128, 0, stream>>>(x, tstar, padflag);
  gather2_kernel<<<40960, 256, 0, stream>>>(x, embed, inp2);
  wih3_kernel<<<5120, 256, 0, stream>>>(Wih, wih3);
  lstm_scan<<<NBLK, 256, 0, stream>>>(Whh, wih3, bih, bhh, inp2, tstar, padflag,
                                      h_pk, hsel, flags);
  head_kernel<<<Bn, 64, 0, stream>>>(hsel, Wout, bout, out);
}